// Round 3
// baseline (316.486 us; speedup 1.0000x reference)
//
#include <hip/hip_runtime.h>

#define B 4
#define M 8192
#define NSTY 8192
#define KNB 8
#define F 288
#define NT (M + NSTY)   // 16384
#define BM (B * M)      // 32768

typedef __attribute__((ext_vector_type(8))) short short8;
typedef __attribute__((ext_vector_type(4))) float floatx4;

__device__ __forceinline__ float b2f(unsigned short h) {
    union { unsigned int u; float f; } c; c.u = ((unsigned int)h) << 16; return c.f;
}
__device__ __forceinline__ unsigned short f2b(float x) {
    union { float f; unsigned int u; } c; c.f = x;
    unsigned int r = c.u + 0x7FFFu + ((c.u >> 16) & 1u);
    return (unsigned short)(r >> 16);
}
__device__ __forceinline__ void gload_lds16(const void* g, void* l) {
    __builtin_amdgcn_global_load_lds(
        (const __attribute__((address_space(1))) unsigned int*)g,
        (__attribute__((address_space(3))) unsigned int*)l, 16, 0, 0);
}

// ---------------- degree histogram + rsqrt ----------------
__global__ void deg_kernel(const int* __restrict__ idx_k1, const int* __restrict__ idx_k2,
                           int* __restrict__ deg) {
    int t = blockIdx.x * blockDim.x + threadIdx.x;
    if (t >= B * M * KNB) return;
    int b = t / (M * KNB);
    atomicAdd(&deg[b * NT + idx_k2[t]], 1);
    atomicAdd(&deg[b * NT + M + idx_k1[t]], 1);
}

__global__ void rsqrt_kernel(float* __restrict__ dsc) {
    int t = blockIdx.x * blockDim.x + threadIdx.x;
    if (t >= B * NT) return;
    int d = ((const int*)dsc)[t];
    dsc[t] = rsqrtf((float)(d < 1 ? 1 : d));
}

// ---------------- pack W1,W2 [F][F] fp32 -> Wp [F/8][F][8] bf16 ----------------
__global__ void packw_kernel(const float* __restrict__ W1, const float* __restrict__ W2,
                             unsigned short* __restrict__ Wp1, unsigned short* __restrict__ Wp2) {
    int t = blockIdx.x * 256 + threadIdx.x;
    if (t >= 2 * F * F) return;
    int half = t >= F * F;
    int tt = t - half * F * F;
    int k = tt / F, n = tt - k * F;
    const float* W = half ? W2 : W1;
    unsigned short* Wp = half ? Wp2 : Wp1;
    Wp[((size_t)(k >> 3) * F + n) * 8 + (k & 7)] = f2b(W[tt]);
}

// ---------------- convert feat_c|feat_s fp32 -> featb [B][NT][F] bf16 ----------------
__global__ void convert_kernel(const float* __restrict__ fc, const float* __restrict__ fs,
                               unsigned short* __restrict__ fb) {
    unsigned int t = blockIdx.x * 256 + threadIdx.x;
    unsigned int e = t * 4;
    if (e >= (unsigned int)(B) * NT * F) return;
    int row = (int)(e / F);
    int f = (int)(e - (unsigned int)row * F);
    int b = row >> 14, v = row & (NT - 1);
    const float* src = (v < M) ? fc + ((size_t)b * M + v) * F + f
                               : fs + ((size_t)b * NSTY + (v - M)) * F + f;
    float4 x = *(const float4*)src;
    uint2 o;
    o.x = (unsigned int)f2b(x.x) | ((unsigned int)f2b(x.y) << 16);
    o.y = (unsigned int)f2b(x.z) | ((unsigned int)f2b(x.w) << 16);
    *(uint2*)(fb + e) = o;
}

// ---------------- fused gather + MFMA GEMM ----------------
// LAYER 1: gather 16 nbrs from featb [B][NT][F], GEMM W1 + b1, relu, bf16 out (h1b)
// LAYER 2: gather 8 content nbrs from h1b [B][M][F] + style const term, GEMM W2 + b2, fp32 out
// XCD batch-affinity swizzle: blockIdx%8 -> XCD (round-robin); batch = (blockIdx&7)>>1.
template<int LAYER>
__global__ __launch_bounds__(256, 2) void fused_kernel(
        const unsigned short* __restrict__ src_tbl,
        const int* __restrict__ idx_k1, const int* __restrict__ idx_k2,
        const float* __restrict__ dsc, const float* __restrict__ b1,
        const unsigned short* __restrict__ Wp, const float* __restrict__ bias,
        void* __restrict__ Cout) {
    __shared__ __align__(16) unsigned short sA[64 * F];        // 36864 B
    __shared__ __align__(16) unsigned short sB[2][4 * F * 8];  // 2 x 18432 B
    int tid = threadIdx.x, wid = tid >> 6, lane = tid & 63;
    int rx = blockIdx.x & 7, q = blockIdx.x >> 3;
    int b = rx >> 1;                      // batch (2 XCDs per batch)
    int sub = q * 2 + (rx & 1);           // tile within batch [0,128)
    int gr0 = b * M + sub * 64;           // global dst row base

    // stage first B chunk early (drained by the phase-boundary barrier)
    if (tid < 128) {
        #pragma unroll
        for (int rr = 0; rr < 9; ++rr)
            gload_lds16(Wp + (rr * 128 + tid) * 8, &sB[0][(rr * 128 + tid) * 8]);
    }

    // ---- phase 1: gather this block's 64 dst rows into sA (16 rows per wave) ----
    float rb[4] = {0.f,0.f,0.f,0.f}, rbt[4] = {0.f,0.f,0.f,0.f};
    if (LAYER == 2) {
        float4 t4 = *(const float4*)(b1 + 4 * lane);
        rb[0]=fmaxf(t4.x,0.f); rb[1]=fmaxf(t4.y,0.f); rb[2]=fmaxf(t4.z,0.f); rb[3]=fmaxf(t4.w,0.f);
        if (lane < 8) {
            float4 t5 = *(const float4*)(b1 + 256 + 4 * lane);
            rbt[0]=fmaxf(t5.x,0.f); rbt[1]=fmaxf(t5.y,0.f); rbt[2]=fmaxf(t5.z,0.f); rbt[3]=fmaxf(t5.w,0.f);
        }
    }
    const unsigned short* base = src_tbl + (size_t)b * (LAYER == 1 ? NT : M) * F;

    int cu = 0, nu = 0; float cw = 0.f, nw = 0.f;
    // load (u,w) for row t into lanes 0..15
    {
        size_t e = (size_t)(gr0 + wid * 16) * KNB;
        if (lane < 8)       { cu = idx_k2[e + lane]; cw = dsc[b * NT + cu]; }
        else if (lane < 16) { cu = M + idx_k1[e + lane - 8]; cw = dsc[b * NT + cu]; }
    }
    for (int t = 0; t < 16; ++t) {
        if (t < 15) {   // prefetch next row's indices/weights
            size_t e = (size_t)(gr0 + wid * 16 + t + 1) * KNB;
            nu = 0; nw = 0.f;
            if (lane < 8)       { nu = idx_k2[e + lane]; nw = dsc[b * NT + nu]; }
            else if (lane < 16) { nu = M + idx_k1[e + lane - 8]; nw = dsc[b * NT + nu]; }
        }
        float S = 0.f;
        if (LAYER == 2) {
            #pragma unroll
            for (int k = 8; k < 16; ++k) S += __shfl(cw, k);
        }
        float a0[4], a1[4];
        #pragma unroll
        for (int i = 0; i < 4; ++i) {
            a0[i] = (LAYER == 2) ? rb[i] * S : 0.f;
            a1[i] = (LAYER == 2) ? rbt[i] * S : 0.f;
        }
        #pragma unroll
        for (int k = 0; k < ((LAYER == 1) ? 16 : 8); ++k) {
            int   uk = __shfl(cu, k);
            float wk = __shfl(cw, k);
            const unsigned short* s = base + (size_t)uk * F;
            uint2 d0 = *(const uint2*)(s + 4 * lane);
            a0[0] += wk * b2f((unsigned short)(d0.x & 0xFFFF));
            a0[1] += wk * b2f((unsigned short)(d0.x >> 16));
            a0[2] += wk * b2f((unsigned short)(d0.y & 0xFFFF));
            a0[3] += wk * b2f((unsigned short)(d0.y >> 16));
            if (lane < 8) {
                uint2 d1 = *(const uint2*)(s + 256 + 4 * lane);
                a1[0] += wk * b2f((unsigned short)(d1.x & 0xFFFF));
                a1[1] += wk * b2f((unsigned short)(d1.x >> 16));
                a1[2] += wk * b2f((unsigned short)(d1.y & 0xFFFF));
                a1[3] += wk * b2f((unsigned short)(d1.y >> 16));
            }
        }
        unsigned short* dst = &sA[(wid * 16 + t) * F];
        uint2 o;
        o.x = (unsigned int)f2b(a0[0] * 0.25f) | ((unsigned int)f2b(a0[1] * 0.25f) << 16);
        o.y = (unsigned int)f2b(a0[2] * 0.25f) | ((unsigned int)f2b(a0[3] * 0.25f) << 16);
        *(uint2*)(dst + 4 * lane) = o;
        if (lane < 8) {
            uint2 o1;
            o1.x = (unsigned int)f2b(a1[0] * 0.25f) | ((unsigned int)f2b(a1[1] * 0.25f) << 16);
            o1.y = (unsigned int)f2b(a1[2] * 0.25f) | ((unsigned int)f2b(a1[3] * 0.25f) << 16);
            *(uint2*)(dst + 256 + 4 * lane) = o1;
        }
        cu = nu; cw = nw;
    }
    __syncthreads();

    // ---- phase 2: GEMM sA[64xF] @ Wp -> 64xF, bias (+relu), store ----
    int wm = wid & 1, wn = wid >> 1;
    int quad = lane >> 4, r16 = lane & 15;
    floatx4 acc[9][2];
    #pragma unroll
    for (int ct = 0; ct < 9; ++ct)
        #pragma unroll
        for (int rt = 0; rt < 2; ++rt)
            acc[ct][rt] = (floatx4){0.f, 0.f, 0.f, 0.f};

    for (int s = 0; s < 9; ++s) {
        if (s < 8 && tid < 128) {
            const unsigned short* src = Wp + (size_t)(s + 1) * 4 * F * 8;
            unsigned short* dstb = sB[(s + 1) & 1];
            #pragma unroll
            for (int rr = 0; rr < 9; ++rr)
                gload_lds16(src + (rr * 128 + tid) * 8, dstb + (rr * 128 + tid) * 8);
        }
        short8 a0 = *(const short8*)&sA[(wm * 32 + r16) * F + s * 32 + quad * 8];
        short8 a1 = *(const short8*)&sA[(wm * 32 + 16 + r16) * F + s * 32 + quad * 8];
        const unsigned short* bb = &sB[s & 1][(quad * F + wn * 144 + r16) * 8];
        #pragma unroll
        for (int ct = 0; ct < 9; ++ct) {
            short8 bf = *(const short8*)(bb + ct * 128);
            acc[ct][0] = __builtin_amdgcn_mfma_f32_16x16x32_bf16(a0, bf, acc[ct][0], 0, 0, 0);
            acc[ct][1] = __builtin_amdgcn_mfma_f32_16x16x32_bf16(a1, bf, acc[ct][1], 0, 0, 0);
        }
        __syncthreads();
    }

    #pragma unroll
    for (int ct = 0; ct < 9; ++ct) {
        int col = wn * 144 + ct * 16 + r16;
        float bc = bias[col];
        #pragma unroll
        for (int rt = 0; rt < 2; ++rt) {
            #pragma unroll
            for (int rg = 0; rg < 4; ++rg) {
                float v = acc[ct][rt][rg] + bc;
                int grow = gr0 + wm * 32 + quad * 4 + rt * 16 + rg;
                if (LAYER == 1)
                    ((unsigned short*)Cout)[(size_t)grow * F + col] = f2b(fmaxf(v, 0.f));
                else
                    ((float*)Cout)[(size_t)grow * F + col] = v;
            }
        }
    }
}

extern "C" void kernel_launch(void* const* d_in, const int* in_sizes, int n_in,
                              void* d_out, int out_size, void* d_ws, size_t ws_size,
                              hipStream_t stream) {
    const float* feat_c = (const float*)d_in[0];
    const float* feat_s = (const float*)d_in[1];
    const int*   idx_k1 = (const int*)d_in[2];
    const int*   idx_k2 = (const int*)d_in[3];
    const float* W1     = (const float*)d_in[4];
    const float* b1     = (const float*)d_in[5];
    const float* W2     = (const float*)d_in[6];
    const float* b2     = (const float*)d_in[7];

    // ws layout (16-B aligned)
    char* ws = (char*)d_ws;
    float*          dsc  = (float*)ws;                                  // 256 KB
    unsigned short* Wp1  = (unsigned short*)(ws + 262144);              // 165888 B
    unsigned short* Wp2  = (unsigned short*)(ws + 262144 + 165888);     // 165888 B
    unsigned short* h1b  = (unsigned short*)(ws + 262144 + 2 * 165888); // BM*F*2 = 18.9 MB

    // d_out doubles as bf16 feature table (exactly BM*F*4 == B*NT*F*2 bytes), then final fp32
    unsigned short* featb = (unsigned short*)d_out;
    float*          out   = (float*)d_out;

    hipMemsetAsync(dsc, 0, (size_t)B * NT * sizeof(int), stream);
    deg_kernel<<<(B * M * KNB + 255) / 256, 256, 0, stream>>>(idx_k1, idx_k2, (int*)dsc);
    rsqrt_kernel<<<(B * NT + 255) / 256, 256, 0, stream>>>(dsc);
    packw_kernel<<<(2 * F * F + 255) / 256, 256, 0, stream>>>(W1, W2, Wp1, Wp2);
    convert_kernel<<<(B * NT * F / 4 + 255) / 256, 256, 0, stream>>>(feat_c, feat_s, featb);

    fused_kernel<1><<<BM / 64, 256, 0, stream>>>(featb, idx_k1, idx_k2, dsc, b1, Wp1, b1, (void*)h1b);
    fused_kernel<2><<<BM / 64, 256, 0, stream>>>(h1b,   idx_k1, idx_k2, dsc, b1, Wp2, b2, (void*)out);
}

// Round 4
// 254.224 us; speedup vs baseline: 1.2449x; 1.2449x over previous
//
#include <hip/hip_runtime.h>

#define B 4
#define M 8192
#define NSTY 8192
#define KNB 8
#define F 288
#define NT (M + NSTY)   // 16384
#define BM (B * M)      // 32768

typedef __attribute__((ext_vector_type(8))) short short8;
typedef __attribute__((ext_vector_type(4))) float floatx4;
typedef __attribute__((ext_vector_type(2))) float floatx2;

__device__ __forceinline__ float u2f(unsigned int u) {
    union { unsigned int u; float f; } c; c.u = u; return c.f;
}
__device__ __forceinline__ unsigned short f2b(float x) {
    union { float f; unsigned int u; } c; c.f = x;
    unsigned int r = c.u + 0x7FFFu + ((c.u >> 16) & 1u);
    return (unsigned short)(r >> 16);
}
// bf16 pair (packed in u32) -> two fp32
__device__ __forceinline__ floatx2 bpair(unsigned int p) {
    floatx2 r;
    r.x = u2f(p << 16);
    r.y = u2f(p & 0xFFFF0000u);
    return r;
}
__device__ __forceinline__ void gload_lds16(const void* g, void* l) {
    __builtin_amdgcn_global_load_lds(
        (const __attribute__((address_space(1))) unsigned int*)g,
        (__attribute__((address_space(3))) unsigned int*)l, 16, 0, 0);
}

// ---------------- merged prep: deg histogram | pack W1,W2 | fp32->bf16 convert ----------------
// blocks [0,1024): deg atomics; [1024,19456): convert; [19456,20104): packw
#define PREP_DEG   1024
#define PREP_CVT   18432
#define PREP_PKW   648
__global__ void prep_kernel(const int* __restrict__ idx_k1, const int* __restrict__ idx_k2,
                            int* __restrict__ deg,
                            const float* __restrict__ fc, const float* __restrict__ fs,
                            unsigned short* __restrict__ fb,
                            const float* __restrict__ W1, const float* __restrict__ W2,
                            unsigned short* __restrict__ Wp1, unsigned short* __restrict__ Wp2) {
    int blk = blockIdx.x;
    if (blk < PREP_DEG) {
        int t = blk * 256 + threadIdx.x;            // [0, 262144)
        int b = t / (M * KNB);
        atomicAdd(&deg[b * NT + idx_k2[t]], 1);
        atomicAdd(&deg[b * NT + M + idx_k1[t]], 1);
    } else if (blk < PREP_DEG + PREP_CVT) {
        unsigned int t = (unsigned int)(blk - PREP_DEG) * 256 + threadIdx.x;
        unsigned int e = t * 4;                     // element index in [B][NT][F]
        int row = (int)(e / F);
        int f = (int)(e - (unsigned int)row * F);
        int b = row >> 14, v = row & (NT - 1);
        const float* src = (v < M) ? fc + ((size_t)b * M + v) * F + f
                                   : fs + ((size_t)b * NSTY + (v - M)) * F + f;
        float4 x = *(const float4*)src;
        uint2 o;
        o.x = (unsigned int)f2b(x.x) | ((unsigned int)f2b(x.y) << 16);
        o.y = (unsigned int)f2b(x.z) | ((unsigned int)f2b(x.w) << 16);
        *(uint2*)(fb + e) = o;
    } else {
        int t = (blk - PREP_DEG - PREP_CVT) * 256 + threadIdx.x;
        if (t >= 2 * F * F) return;
        int half = t >= F * F;
        int tt = t - half * F * F;
        int k = tt / F, n = tt - k * F;
        const float* W = half ? W2 : W1;
        unsigned short* Wp = half ? Wp2 : Wp1;
        Wp[((size_t)(k >> 3) * F + n) * 8 + (k & 7)] = f2b(W[tt]);
    }
}

// ---------------- gather kernels (one wave per dst row, 4 rows/block) ----------------
// XCD batch-affinity swizzle: xcd = blk&7, batch = xcd>>1 (2 XCDs per batch).
// LAYER 1: 16 nbrs from featb [B][NT][F]; LAYER 2: 8 content nbrs of h1b + style const term.
template<int LAYER>
__global__ void agg_kernel(const unsigned short* __restrict__ src_tbl,
                           const int* __restrict__ idx_k1, const int* __restrict__ idx_k2,
                           const int* __restrict__ deg, const float* __restrict__ b1,
                           unsigned short* __restrict__ aggb) {
    int wid = threadIdx.x >> 6, lane = threadIdx.x & 63;
    int blk = blockIdx.x;
    int rx = blk & 7;
    int b = rx >> 1;
    int sub = (blk >> 3) * 2 + (rx & 1);        // [0, 2048) row-group within batch
    int r = sub * 4 + wid;                      // dst row within batch [0, M)
    size_t ebase = ((size_t)b * M + r) * KNB;

    int u = 0; float w = 0.f;
    if (lane < 8) {
        u = idx_k2[ebase + lane];
        int d = deg[b * NT + u];
        w = rsqrtf((float)(d < 1 ? 1 : d));
    } else if (lane < 16) {
        u = M + idx_k1[ebase + lane - 8];
        int d = deg[b * NT + u];
        w = rsqrtf((float)(d < 1 ? 1 : d));
    }

    floatx2 a0[2] = {{0.f,0.f},{0.f,0.f}};
    floatx2 a1[2] = {{0.f,0.f},{0.f,0.f}};
    if (LAYER == 2) {
        float S = 0.f;
        #pragma unroll
        for (int k = 8; k < 16; ++k) S += __shfl(w, k);
        float4 t4 = *(const float4*)(b1 + 4 * lane);
        a0[0].x = fmaxf(t4.x, 0.f) * S; a0[0].y = fmaxf(t4.y, 0.f) * S;
        a0[1].x = fmaxf(t4.z, 0.f) * S; a0[1].y = fmaxf(t4.w, 0.f) * S;
        if (lane < 8) {
            float4 t5 = *(const float4*)(b1 + 256 + 4 * lane);
            a1[0].x = fmaxf(t5.x, 0.f) * S; a1[0].y = fmaxf(t5.y, 0.f) * S;
            a1[1].x = fmaxf(t5.z, 0.f) * S; a1[1].y = fmaxf(t5.w, 0.f) * S;
        }
    }

    const unsigned short* base = src_tbl + (size_t)b * (LAYER == 1 ? NT : M) * F;
    #pragma unroll
    for (int k = 0; k < ((LAYER == 1) ? 16 : 8); ++k) {
        int   uk = __shfl(u, k);
        float wk = __shfl(w, k);
        floatx2 wk2 = {wk, wk};
        const unsigned short* s = base + (size_t)uk * F;
        uint2 d0 = *(const uint2*)(s + 4 * lane);
        a0[0] += wk2 * bpair(d0.x);
        a0[1] += wk2 * bpair(d0.y);
        if (lane < 8) {
            uint2 d1 = *(const uint2*)(s + 256 + 4 * lane);
            a1[0] += wk2 * bpair(d1.x);
            a1[1] += wk2 * bpair(d1.y);
        }
    }

    unsigned short* dst = aggb + ((size_t)b * M + r) * F;
    uint2 o;
    o.x = (unsigned int)f2b(a0[0].x * 0.25f) | ((unsigned int)f2b(a0[0].y * 0.25f) << 16);
    o.y = (unsigned int)f2b(a0[1].x * 0.25f) | ((unsigned int)f2b(a0[1].y * 0.25f) << 16);
    *(uint2*)(dst + 4 * lane) = o;
    if (lane < 8) {
        uint2 o1;
        o1.x = (unsigned int)f2b(a1[0].x * 0.25f) | ((unsigned int)f2b(a1[0].y * 0.25f) << 16);
        o1.y = (unsigned int)f2b(a1[1].x * 0.25f) | ((unsigned int)f2b(a1[1].y * 0.25f) << 16);
        *(uint2*)(dst + 256 + 4 * lane) = o1;
    }
}

// ---------------- bf16 MFMA GEMM: C[64 rows x 288] = A @ Wp + bias, batch-swizzled ----------------
template<int RELU, int OUTBF16>
__global__ __launch_bounds__(256, 2) void gemm_kernel(
        const unsigned short* __restrict__ A,   // [BM][F] bf16
        const unsigned short* __restrict__ Wp,  // [F/8][F][8] bf16 packed
        const float* __restrict__ bias,
        void* __restrict__ Cout) {
    __shared__ __align__(16) unsigned short sA[64 * F];        // 36864 B
    __shared__ __align__(16) unsigned short sB[2][4 * F * 8];  // 2 x 18432 B
    int tid = threadIdx.x;
    int wid = tid >> 6, lane = tid & 63;
    int wm = wid & 1, wn = wid >> 1;
    int quad = lane >> 4, r16 = lane & 15;
    int blk = blockIdx.x;
    int rx = blk & 7;
    int b = rx >> 1;
    int sub = (blk >> 3) * 2 + (rx & 1);        // [0, 128) tile within batch
    int row0 = b * M + sub * 64;

    const unsigned short* Ab = A + (size_t)row0 * F;
    #pragma unroll
    for (int rr = 0; rr < 9; ++rr)
        gload_lds16(Ab + (rr * 256 + tid) * 8, &sA[(rr * 256 + tid) * 8]);
    if (tid < 128) {
        #pragma unroll
        for (int rr = 0; rr < 9; ++rr)
            gload_lds16(Wp + (rr * 128 + tid) * 8, &sB[0][(rr * 128 + tid) * 8]);
    }

    floatx4 acc[9][2];
    #pragma unroll
    for (int ct = 0; ct < 9; ++ct)
        #pragma unroll
        for (int rt = 0; rt < 2; ++rt)
            acc[ct][rt] = (floatx4){0.f, 0.f, 0.f, 0.f};

    __syncthreads();

    for (int s = 0; s < 9; ++s) {
        if (s < 8 && tid < 128) {
            const unsigned short* src = Wp + (size_t)(s + 1) * 4 * F * 8;
            unsigned short* dstb = sB[(s + 1) & 1];
            #pragma unroll
            for (int rr = 0; rr < 9; ++rr)
                gload_lds16(src + (rr * 128 + tid) * 8, dstb + (rr * 128 + tid) * 8);
        }
        short8 a0 = *(const short8*)&sA[(wm * 32 + r16) * F + s * 32 + quad * 8];
        short8 a1 = *(const short8*)&sA[(wm * 32 + 16 + r16) * F + s * 32 + quad * 8];
        const unsigned short* bb = &sB[s & 1][(quad * F + wn * 144 + r16) * 8];
        #pragma unroll
        for (int ct = 0; ct < 9; ++ct) {
            short8 bf = *(const short8*)(bb + ct * 128);
            acc[ct][0] = __builtin_amdgcn_mfma_f32_16x16x32_bf16(a0, bf, acc[ct][0], 0, 0, 0);
            acc[ct][1] = __builtin_amdgcn_mfma_f32_16x16x32_bf16(a1, bf, acc[ct][1], 0, 0, 0);
        }
        __syncthreads();
    }

    #pragma unroll
    for (int ct = 0; ct < 9; ++ct) {
        int col = wn * 144 + ct * 16 + r16;
        float bc = bias[col];
        #pragma unroll
        for (int rt = 0; rt < 2; ++rt) {
            #pragma unroll
            for (int rg = 0; rg < 4; ++rg) {
                float v = acc[ct][rt][rg] + bc;
                if (RELU) v = fmaxf(v, 0.f);
                int grow = row0 + wm * 32 + quad * 4 + rt * 16 + rg;
                if (OUTBF16) ((unsigned short*)Cout)[(size_t)grow * F + col] = f2b(v);
                else         ((float*)Cout)[(size_t)grow * F + col] = v;
            }
        }
    }
}

extern "C" void kernel_launch(void* const* d_in, const int* in_sizes, int n_in,
                              void* d_out, int out_size, void* d_ws, size_t ws_size,
                              hipStream_t stream) {
    const float* feat_c = (const float*)d_in[0];
    const float* feat_s = (const float*)d_in[1];
    const int*   idx_k1 = (const int*)d_in[2];
    const int*   idx_k2 = (const int*)d_in[3];
    const float* W1     = (const float*)d_in[4];
    const float* b1     = (const float*)d_in[5];
    const float* W2     = (const float*)d_in[6];
    const float* b2     = (const float*)d_in[7];

    // ws layout (16-B aligned)
    char* ws = (char*)d_ws;
    int*            deg  = (int*)ws;                                    // 256 KB
    unsigned short* Wp1  = (unsigned short*)(ws + 262144);              // 165888 B
    unsigned short* Wp2  = (unsigned short*)(ws + 262144 + 165888);     // 165888 B
    unsigned short* aggb = (unsigned short*)(ws + 262144 + 2 * 165888); // BM*F*2 = 18.9 MB

    // d_out doubles as bf16 feature table (B*NT*F*2 == out bytes), then bf16 h1, then final fp32
    unsigned short* featb = (unsigned short*)d_out;
    unsigned short* h1b   = (unsigned short*)d_out;
    float*          out   = (float*)d_out;

    hipMemsetAsync(deg, 0, (size_t)B * NT * sizeof(int), stream);
    prep_kernel<<<PREP_DEG + PREP_CVT + PREP_PKW, 256, 0, stream>>>(
        idx_k1, idx_k2, deg, feat_c, feat_s, featb, W1, W2, Wp1, Wp2);

    agg_kernel<1><<<BM / 4, 256, 0, stream>>>(featb, idx_k1, idx_k2, deg, b1, aggb);
    gemm_kernel<1, 1><<<BM / 64, 256, 0, stream>>>(aggb, Wp1, b1, (void*)h1b);

    agg_kernel<2><<<BM / 4, 256, 0, stream>>>(h1b, idx_k1, idx_k2, deg, b1, aggb);
    gemm_kernel<0, 0><<<BM / 64, 256, 0, stream>>>(aggb, Wp2, b2, (void*)out);
}

// Round 5
// 229.954 us; speedup vs baseline: 1.3763x; 1.1055x over previous
//
#include <hip/hip_runtime.h>

#define B 4
#define M 8192
#define NSTY 8192
#define KNB 8
#define F 288
#define NT (M + NSTY)   // 16384
#define BM (B * M)      // 32768

typedef __attribute__((ext_vector_type(8))) short short8;
typedef __attribute__((ext_vector_type(4))) float floatx4;
typedef __attribute__((ext_vector_type(2))) float floatx2;

__device__ __forceinline__ float u2f(unsigned int u) {
    union { unsigned int u; float f; } c; c.u = u; return c.f;
}
__device__ __forceinline__ unsigned short f2b(float x) {
    union { float f; unsigned int u; } c; c.f = x;
    unsigned int r = c.u + 0x7FFFu + ((c.u >> 16) & 1u);
    return (unsigned short)(r >> 16);
}
__device__ __forceinline__ floatx2 bpair(unsigned int p) {
    floatx2 r;
    r.x = u2f(p << 16);
    r.y = u2f(p & 0xFFFF0000u);
    return r;
}
__device__ __forceinline__ void gload_lds16(const void* g, void* l) {
    __builtin_amdgcn_global_load_lds(
        (const __attribute__((address_space(1))) unsigned int*)g,
        (__attribute__((address_space(3))) unsigned int*)l, 16, 0, 0);
}

// ---------------- merged prep: deg histogram | pack W1,W2 | fp32->bf16 convert ----------------
#define PREP_DEG   1024
#define PREP_CVT   18432
#define PREP_PKW   648
__global__ void prep_kernel(const int* __restrict__ idx_k1, const int* __restrict__ idx_k2,
                            int* __restrict__ deg,
                            const float* __restrict__ fc, const float* __restrict__ fs,
                            unsigned short* __restrict__ fb,
                            const float* __restrict__ W1, const float* __restrict__ W2,
                            unsigned short* __restrict__ Wp1, unsigned short* __restrict__ Wp2) {
    int blk = blockIdx.x;
    if (blk < PREP_DEG) {
        int t = blk * 256 + threadIdx.x;
        int b = t / (M * KNB);
        atomicAdd(&deg[b * NT + idx_k2[t]], 1);
        atomicAdd(&deg[b * NT + M + idx_k1[t]], 1);
    } else if (blk < PREP_DEG + PREP_CVT) {
        unsigned int t = (unsigned int)(blk - PREP_DEG) * 256 + threadIdx.x;
        unsigned int e = t * 4;
        int row = (int)(e / F);
        int f = (int)(e - (unsigned int)row * F);
        int b = row >> 14, v = row & (NT - 1);
        const float* src = (v < M) ? fc + ((size_t)b * M + v) * F + f
                                   : fs + ((size_t)b * NSTY + (v - M)) * F + f;
        float4 x = *(const float4*)src;
        uint2 o;
        o.x = (unsigned int)f2b(x.x) | ((unsigned int)f2b(x.y) << 16);
        o.y = (unsigned int)f2b(x.z) | ((unsigned int)f2b(x.w) << 16);
        *(uint2*)(fb + e) = o;
    } else {
        int t = (blk - PREP_DEG - PREP_CVT) * 256 + threadIdx.x;
        if (t >= 2 * F * F) return;
        int half = t >= F * F;
        int tt = t - half * F * F;
        int k = tt / F, n = tt - k * F;
        const float* W = half ? W2 : W1;
        unsigned short* Wp = half ? Wp2 : Wp1;
        Wp[((size_t)(k >> 3) * F + n) * 8 + (k & 7)] = f2b(W[tt]);
    }
}

// ---------------- gather kernels: 4 rows per wave, uint4 row loads over 36 lanes ----------------
// Prologue: 64 lanes = 4 rows x 16 edges, fully coalesced idx load + random deg load.
// XCD batch-affinity: xcd = blk&7, batch = xcd>>1.
template<int LAYER>
__global__ __launch_bounds__(256) void agg_kernel(
        const unsigned short* __restrict__ src_tbl,
        const int* __restrict__ idx_k1, const int* __restrict__ idx_k2,
        const int* __restrict__ deg, const float* __restrict__ b1,
        unsigned short* __restrict__ aggb) {
    const int NK = (LAYER == 1) ? 16 : 8;
    int tid = threadIdx.x, wid = tid >> 6, lane = tid & 63;
    int blk = blockIdx.x;
    int rx = blk & 7;
    int b = rx >> 1;
    int sub = (blk >> 3) * 2 + (rx & 1);      // [0, 512) 16-row group within batch
    int rbase = sub * 16 + wid * 4;           // this wave's 4 rows

    // prologue: lane = i*16 + e  (row i in [0,4), edge e in [0,16))
    int i4 = lane >> 4, e = lane & 15;
    {
        size_t eb = ((size_t)b * M + rbase + i4) * KNB;
        // coalesced: 32 contiguous ints from idx_k2 (e<8) and idx_k1 (e>=8)
    }
    size_t eb = ((size_t)b * M + rbase + i4) * KNB;
    int u;
    if (e < 8) u = idx_k2[eb + e];
    else       u = M + idx_k1[eb + e - 8];
    int dg = deg[b * NT + u];
    float w = rsqrtf((float)(dg < 1 ? 1 : dg));
    float wst = (e >= 8) ? w : 0.f;           // style-edge weight (for LAYER 2 const term)

    // bias (LAYER 2): per-lane 8 features [8*lane, 8*lane+8)
    float bb[8];
    if (LAYER == 2 && lane < 36) {
        float4 t0 = *(const float4*)(b1 + 8 * lane);
        float4 t1 = *(const float4*)(b1 + 8 * lane + 4);
        bb[0]=fmaxf(t0.x,0.f); bb[1]=fmaxf(t0.y,0.f); bb[2]=fmaxf(t0.z,0.f); bb[3]=fmaxf(t0.w,0.f);
        bb[4]=fmaxf(t1.x,0.f); bb[5]=fmaxf(t1.y,0.f); bb[6]=fmaxf(t1.z,0.f); bb[7]=fmaxf(t1.w,0.f);
    }

    const unsigned short* base = src_tbl + (size_t)b * (LAYER == 1 ? NT : M) * F;
    unsigned short* dbase = aggb + ((size_t)b * M + rbase) * F;

    #pragma unroll
    for (int i = 0; i < 4; ++i) {
        floatx2 acc[4];
        if (LAYER == 2) {
            float S = 0.f;
            #pragma unroll
            for (int j = 8; j < 16; ++j) S += __shfl(wst, i * 16 + j);
            #pragma unroll
            for (int j = 0; j < 4; ++j) { acc[j].x = bb[2*j] * S; acc[j].y = bb[2*j+1] * S; }
        } else {
            #pragma unroll
            for (int j = 0; j < 4; ++j) acc[j] = (floatx2){0.f, 0.f};
        }

        // gather NK neighbor rows in chunks of 8 (8 dwordx4 loads in flight)
        #pragma unroll
        for (int c = 0; c < NK / 8; ++c) {
            const unsigned short* sp[8];
            #pragma unroll
            for (int k = 0; k < 8; ++k) {
                int uk = __shfl(u, i * 16 + c * 8 + k);
                sp[k] = base + (size_t)uk * F + 8 * lane;
            }
            uint4 v[8];
            if (lane < 36) {
                #pragma unroll
                for (int k = 0; k < 8; ++k) v[k] = *(const uint4*)sp[k];
            }
            #pragma unroll
            for (int k = 0; k < 8; ++k) {
                float wk = __shfl(w, i * 16 + c * 8 + k);
                floatx2 wk2 = {wk, wk};
                acc[0] += wk2 * bpair(v[k].x);
                acc[1] += wk2 * bpair(v[k].y);
                acc[2] += wk2 * bpair(v[k].z);
                acc[3] += wk2 * bpair(v[k].w);
            }
        }

        if (lane < 36) {
            uint4 o;
            o.x = (unsigned int)f2b(acc[0].x*0.25f) | ((unsigned int)f2b(acc[0].y*0.25f) << 16);
            o.y = (unsigned int)f2b(acc[1].x*0.25f) | ((unsigned int)f2b(acc[1].y*0.25f) << 16);
            o.z = (unsigned int)f2b(acc[2].x*0.25f) | ((unsigned int)f2b(acc[2].y*0.25f) << 16);
            o.w = (unsigned int)f2b(acc[3].x*0.25f) | ((unsigned int)f2b(acc[3].y*0.25f) << 16);
            *(uint4*)(dbase + (size_t)i * F + 8 * lane) = o;
        }
    }
}

// ---------------- bf16 MFMA GEMM: C[64 rows x 288] = A @ Wp + bias, batch-swizzled ----------------
template<int RELU, int OUTBF16>
__global__ __launch_bounds__(256, 2) void gemm_kernel(
        const unsigned short* __restrict__ A,
        const unsigned short* __restrict__ Wp,
        const float* __restrict__ bias,
        void* __restrict__ Cout) {
    __shared__ __align__(16) unsigned short sA[64 * F];
    __shared__ __align__(16) unsigned short sB[2][4 * F * 8];
    int tid = threadIdx.x;
    int wid = tid >> 6, lane = tid & 63;
    int wm = wid & 1, wn = wid >> 1;
    int quad = lane >> 4, r16 = lane & 15;
    int blk = blockIdx.x;
    int rx = blk & 7;
    int b = rx >> 1;
    int sub = (blk >> 3) * 2 + (rx & 1);
    int row0 = b * M + sub * 64;

    const unsigned short* Ab = A + (size_t)row0 * F;
    #pragma unroll
    for (int rr = 0; rr < 9; ++rr)
        gload_lds16(Ab + (rr * 256 + tid) * 8, &sA[(rr * 256 + tid) * 8]);
    if (tid < 128) {
        #pragma unroll
        for (int rr = 0; rr < 9; ++rr)
            gload_lds16(Wp + (rr * 128 + tid) * 8, &sB[0][(rr * 128 + tid) * 8]);
    }

    floatx4 acc[9][2];
    #pragma unroll
    for (int ct = 0; ct < 9; ++ct)
        #pragma unroll
        for (int rt = 0; rt < 2; ++rt)
            acc[ct][rt] = (floatx4){0.f, 0.f, 0.f, 0.f};

    __syncthreads();

    for (int s = 0; s < 9; ++s) {
        if (s < 8 && tid < 128) {
            const unsigned short* src = Wp + (size_t)(s + 1) * 4 * F * 8;
            unsigned short* dstb = sB[(s + 1) & 1];
            #pragma unroll
            for (int rr = 0; rr < 9; ++rr)
                gload_lds16(src + (rr * 128 + tid) * 8, dstb + (rr * 128 + tid) * 8);
        }
        short8 a0 = *(const short8*)&sA[(wm * 32 + r16) * F + s * 32 + quad * 8];
        short8 a1 = *(const short8*)&sA[(wm * 32 + 16 + r16) * F + s * 32 + quad * 8];
        const unsigned short* bbp = &sB[s & 1][(quad * F + wn * 144 + r16) * 8];
        #pragma unroll
        for (int ct = 0; ct < 9; ++ct) {
            short8 bf = *(const short8*)(bbp + ct * 128);
            acc[ct][0] = __builtin_amdgcn_mfma_f32_16x16x32_bf16(a0, bf, acc[ct][0], 0, 0, 0);
            acc[ct][1] = __builtin_amdgcn_mfma_f32_16x16x32_bf16(a1, bf, acc[ct][1], 0, 0, 0);
        }
        __syncthreads();
    }

    #pragma unroll
    for (int ct = 0; ct < 9; ++ct) {
        int col = wn * 144 + ct * 16 + r16;
        float bc = bias[col];
        #pragma unroll
        for (int rt = 0; rt < 2; ++rt) {
            #pragma unroll
            for (int rg = 0; rg < 4; ++rg) {
                float v = acc[ct][rt][rg] + bc;
                if (RELU) v = fmaxf(v, 0.f);
                int grow = row0 + wm * 32 + quad * 4 + rt * 16 + rg;
                if (OUTBF16) ((unsigned short*)Cout)[(size_t)grow * F + col] = f2b(v);
                else         ((float*)Cout)[(size_t)grow * F + col] = v;
            }
        }
    }
}

extern "C" void kernel_launch(void* const* d_in, const int* in_sizes, int n_in,
                              void* d_out, int out_size, void* d_ws, size_t ws_size,
                              hipStream_t stream) {
    const float* feat_c = (const float*)d_in[0];
    const float* feat_s = (const float*)d_in[1];
    const int*   idx_k1 = (const int*)d_in[2];
    const int*   idx_k2 = (const int*)d_in[3];
    const float* W1     = (const float*)d_in[4];
    const float* b1     = (const float*)d_in[5];
    const float* W2     = (const float*)d_in[6];
    const float* b2     = (const float*)d_in[7];

    char* ws = (char*)d_ws;
    int*            deg  = (int*)ws;                                    // 256 KB
    unsigned short* Wp1  = (unsigned short*)(ws + 262144);
    unsigned short* Wp2  = (unsigned short*)(ws + 262144 + 165888);
    unsigned short* aggb = (unsigned short*)(ws + 262144 + 2 * 165888); // 18.9 MB

    unsigned short* featb = (unsigned short*)d_out;  // 37.75 MB bf16 table
    unsigned short* h1b   = (unsigned short*)d_out;  // first 18.9 MB, after agg1 done
    float*          out   = (float*)d_out;

    hipMemsetAsync(deg, 0, (size_t)B * NT * sizeof(int), stream);
    prep_kernel<<<PREP_DEG + PREP_CVT + PREP_PKW, 256, 0, stream>>>(
        idx_k1, idx_k2, deg, feat_c, feat_s, featb, W1, W2, Wp1, Wp2);

    agg_kernel<1><<<BM / 16, 256, 0, stream>>>(featb, idx_k1, idx_k2, deg, b1, aggb);
    gemm_kernel<1, 1><<<BM / 64, 256, 0, stream>>>(aggb, Wp1, b1, (void*)h1b);

    agg_kernel<2><<<BM / 16, 256, 0, stream>>>(h1b, idx_k1, idx_k2, deg, b1, aggb);
    gemm_kernel<0, 0><<<BM / 64, 256, 0, stream>>>(aggb, Wp2, b2, (void*)out);
}

// Round 6
// 229.758 us; speedup vs baseline: 1.3775x; 1.0009x over previous
//
#include <hip/hip_runtime.h>

#define B 4
#define M 8192
#define NSTY 8192
#define KNB 8
#define F 288
#define NT (M + NSTY)   // 16384
#define BM (B * M)      // 32768
#define SEGL (M * F)    // 2359296 elements per convert segment

typedef __attribute__((ext_vector_type(8))) short short8;
typedef __attribute__((ext_vector_type(4))) float floatx4;
typedef __attribute__((ext_vector_type(2))) float floatx2;

__device__ __forceinline__ float u2f(unsigned int u) {
    union { unsigned int u; float f; } c; c.u = u; return c.f;
}
__device__ __forceinline__ unsigned short f2b(float x) {
    union { float f; unsigned int u; } c; c.f = x;
    unsigned int r = c.u + 0x7FFFu + ((c.u >> 16) & 1u);
    return (unsigned short)(r >> 16);
}
__device__ __forceinline__ floatx2 bpair(unsigned int p) {
    floatx2 r;
    r.x = u2f(p << 16);
    r.y = u2f(p & 0xFFFF0000u);
    return r;
}
__device__ __forceinline__ void gload_lds16(const void* g, void* l) {
    __builtin_amdgcn_global_load_lds(
        (const __attribute__((address_space(1))) unsigned int*)g,
        (__attribute__((address_space(3))) unsigned int*)l, 16, 0, 0);
}

// ---------------- merged prep: convert (segment-linear) | deg histogram | pack W ----------------
// Convert FIRST so streaming fills the machine; atomic blocks last.
#define PREP_CVT   9216    // 8 segments x 1152 blocks; 2048 elems/block
#define PREP_DEG   1024
#define PREP_PKW   648
__global__ void prep_kernel(const int* __restrict__ idx_k1, const int* __restrict__ idx_k2,
                            int* __restrict__ deg,
                            const float* __restrict__ fc, const float* __restrict__ fs,
                            unsigned short* __restrict__ fb,
                            const float* __restrict__ W1, const float* __restrict__ W2,
                            unsigned short* __restrict__ Wp1, unsigned short* __restrict__ Wp2) {
    int blk = blockIdx.x;
    if (blk < PREP_CVT) {
        // featb[b][0:M][F] <- feat_c[b]; featb[b][M:NT][F] <- feat_s[b]; pure linear copy.
        int seg = blk / 1152;                 // const divisor -> magic mul
        int bis = blk - seg * 1152;
        int b = seg >> 1, sty = seg & 1;
        unsigned int e = (unsigned int)bis * 2048 + threadIdx.x * 8;
        const float* src = (sty ? fs : fc) + (size_t)b * SEGL + e;
        float4 x0 = *(const float4*)src;
        float4 x1 = *(const float4*)(src + 4);
        uint4 o;
        o.x = (unsigned int)f2b(x0.x) | ((unsigned int)f2b(x0.y) << 16);
        o.y = (unsigned int)f2b(x0.z) | ((unsigned int)f2b(x0.w) << 16);
        o.z = (unsigned int)f2b(x1.x) | ((unsigned int)f2b(x1.y) << 16);
        o.w = (unsigned int)f2b(x1.z) | ((unsigned int)f2b(x1.w) << 16);
        *(uint4*)(fb + (size_t)b * 2 * SEGL + (size_t)sty * SEGL + e) = o;
    } else if (blk < PREP_CVT + PREP_DEG) {
        int t = (blk - PREP_CVT) * 256 + threadIdx.x;   // [0, 262144)
        int b = t >> 16;                                 // M*KNB == 65536
        atomicAdd(&deg[b * NT + idx_k2[t]], 1);
        atomicAdd(&deg[b * NT + M + idx_k1[t]], 1);
    } else {
        int t = (blk - PREP_CVT - PREP_DEG) * 256 + threadIdx.x;
        if (t >= 2 * F * F) return;
        int half = t >= F * F;
        int tt = t - half * F * F;
        int k = tt / F, n = tt - k * F;
        const float* W = half ? W2 : W1;
        unsigned short* Wp = half ? Wp2 : Wp1;
        Wp[((size_t)(k >> 3) * F + n) * 8 + (k & 7)] = f2b(W[tt]);
    }
}

// ---------------- gather kernels: 4 rows per wave, uint4 row loads over 36 lanes ----------------
// Prologue: 64 lanes = 4 rows x 16 edges, coalesced idx load + random deg load.
// XCD batch-affinity: xcd = blk&7, batch = xcd>>1.
template<int LAYER>
__global__ __launch_bounds__(256) void agg_kernel(
        const unsigned short* __restrict__ src_tbl,
        const int* __restrict__ idx_k1, const int* __restrict__ idx_k2,
        const int* __restrict__ deg, const float* __restrict__ b1,
        unsigned short* __restrict__ aggb) {
    const int NK = (LAYER == 1) ? 16 : 8;
    int tid = threadIdx.x, wid = tid >> 6, lane = tid & 63;
    int blk = blockIdx.x;
    int rx = blk & 7;
    int b = rx >> 1;
    int sub = (blk >> 3) * 2 + (rx & 1);      // [0, 512) 16-row group within batch
    int rbase = sub * 16 + wid * 4;           // this wave's 4 rows

    // prologue: lane = i*16 + e  (row i in [0,4), edge e in [0,16))
    int i4 = lane >> 4, e = lane & 15;
    size_t eb = ((size_t)b * M + rbase + i4) * KNB;
    int u;
    if (e < 8) u = idx_k2[eb + e];
    else       u = M + idx_k1[eb + e - 8];
    int dg = deg[b * NT + u];
    float w = rsqrtf((float)(dg < 1 ? 1 : dg));
    float wst = (e >= 8) ? w : 0.f;           // style-edge weight (LAYER 2 const term)

    float bb[8];
    if (LAYER == 2 && lane < 36) {
        float4 t0 = *(const float4*)(b1 + 8 * lane);
        float4 t1 = *(const float4*)(b1 + 8 * lane + 4);
        bb[0]=fmaxf(t0.x,0.f); bb[1]=fmaxf(t0.y,0.f); bb[2]=fmaxf(t0.z,0.f); bb[3]=fmaxf(t0.w,0.f);
        bb[4]=fmaxf(t1.x,0.f); bb[5]=fmaxf(t1.y,0.f); bb[6]=fmaxf(t1.z,0.f); bb[7]=fmaxf(t1.w,0.f);
    }

    const unsigned short* base = src_tbl + (size_t)b * (LAYER == 1 ? NT : M) * F;
    unsigned short* dbase = aggb + ((size_t)b * M + rbase) * F;

    #pragma unroll
    for (int i = 0; i < 4; ++i) {
        floatx2 acc[4];
        if (LAYER == 2) {
            float S = 0.f;
            #pragma unroll
            for (int j = 8; j < 16; ++j) S += __shfl(wst, i * 16 + j);
            #pragma unroll
            for (int j = 0; j < 4; ++j) { acc[j].x = bb[2*j] * S; acc[j].y = bb[2*j+1] * S; }
        } else {
            #pragma unroll
            for (int j = 0; j < 4; ++j) acc[j] = (floatx2){0.f, 0.f};
        }

        #pragma unroll
        for (int c = 0; c < NK / 8; ++c) {
            const unsigned short* sp[8];
            #pragma unroll
            for (int k = 0; k < 8; ++k) {
                int uk = __shfl(u, i * 16 + c * 8 + k);
                sp[k] = base + (size_t)uk * F + 8 * lane;
            }
            uint4 v[8];
            if (lane < 36) {
                #pragma unroll
                for (int k = 0; k < 8; ++k) v[k] = *(const uint4*)sp[k];
            }
            #pragma unroll
            for (int k = 0; k < 8; ++k) {
                float wk = __shfl(w, i * 16 + c * 8 + k);
                floatx2 wk2 = {wk, wk};
                acc[0] += wk2 * bpair(v[k].x);
                acc[1] += wk2 * bpair(v[k].y);
                acc[2] += wk2 * bpair(v[k].z);
                acc[3] += wk2 * bpair(v[k].w);
            }
        }

        if (lane < 36) {
            uint4 o;
            o.x = (unsigned int)f2b(acc[0].x*0.25f) | ((unsigned int)f2b(acc[0].y*0.25f) << 16);
            o.y = (unsigned int)f2b(acc[1].x*0.25f) | ((unsigned int)f2b(acc[1].y*0.25f) << 16);
            o.z = (unsigned int)f2b(acc[2].x*0.25f) | ((unsigned int)f2b(acc[2].y*0.25f) << 16);
            o.w = (unsigned int)f2b(acc[3].x*0.25f) | ((unsigned int)f2b(acc[3].y*0.25f) << 16);
            *(uint4*)(dbase + (size_t)i * F + 8 * lane) = o;
        }
    }
}

// ---------------- bf16 MFMA GEMM: C[64 rows x 288] = A @ Wp + bias, batch-swizzled ----------------
template<int RELU, int OUTBF16>
__global__ __launch_bounds__(256, 2) void gemm_kernel(
        const unsigned short* __restrict__ A,
        const unsigned short* __restrict__ Wp,
        const float* __restrict__ bias,
        void* __restrict__ Cout) {
    __shared__ __align__(16) unsigned short sA[64 * F];
    __shared__ __align__(16) unsigned short sB[2][4 * F * 8];
    int tid = threadIdx.x;
    int wid = tid >> 6, lane = tid & 63;
    int wm = wid & 1, wn = wid >> 1;
    int quad = lane >> 4, r16 = lane & 15;
    int blk = blockIdx.x;
    int rx = blk & 7;
    int b = rx >> 1;
    int sub = (blk >> 3) * 2 + (rx & 1);
    int row0 = b * M + sub * 64;

    const unsigned short* Ab = A + (size_t)row0 * F;
    #pragma unroll
    for (int rr = 0; rr < 9; ++rr)
        gload_lds16(Ab + (rr * 256 + tid) * 8, &sA[(rr * 256 + tid) * 8]);
    if (tid < 128) {
        #pragma unroll
        for (int rr = 0; rr < 9; ++rr)
            gload_lds16(Wp + (rr * 128 + tid) * 8, &sB[0][(rr * 128 + tid) * 8]);
    }

    floatx4 acc[9][2];
    #pragma unroll
    for (int ct = 0; ct < 9; ++ct)
        #pragma unroll
        for (int rt = 0; rt < 2; ++rt)
            acc[ct][rt] = (floatx4){0.f, 0.f, 0.f, 0.f};

    __syncthreads();

    for (int s = 0; s < 9; ++s) {
        if (s < 8 && tid < 128) {
            const unsigned short* src = Wp + (size_t)(s + 1) * 4 * F * 8;
            unsigned short* dstb = sB[(s + 1) & 1];
            #pragma unroll
            for (int rr = 0; rr < 9; ++rr)
                gload_lds16(src + (rr * 128 + tid) * 8, dstb + (rr * 128 + tid) * 8);
        }
        short8 a0 = *(const short8*)&sA[(wm * 32 + r16) * F + s * 32 + quad * 8];
        short8 a1 = *(const short8*)&sA[(wm * 32 + 16 + r16) * F + s * 32 + quad * 8];
        const unsigned short* bbp = &sB[s & 1][(quad * F + wn * 144 + r16) * 8];
        #pragma unroll
        for (int ct = 0; ct < 9; ++ct) {
            short8 bf = *(const short8*)(bbp + ct * 128);
            acc[ct][0] = __builtin_amdgcn_mfma_f32_16x16x32_bf16(a0, bf, acc[ct][0], 0, 0, 0);
            acc[ct][1] = __builtin_amdgcn_mfma_f32_16x16x32_bf16(a1, bf, acc[ct][1], 0, 0, 0);
        }
        __syncthreads();
    }

    #pragma unroll
    for (int ct = 0; ct < 9; ++ct) {
        int col = wn * 144 + ct * 16 + r16;
        float bc = bias[col];
        #pragma unroll
        for (int rt = 0; rt < 2; ++rt) {
            #pragma unroll
            for (int rg = 0; rg < 4; ++rg) {
                float v = acc[ct][rt][rg] + bc;
                if (RELU) v = fmaxf(v, 0.f);
                int grow = row0 + wm * 32 + quad * 4 + rt * 16 + rg;
                if (OUTBF16) ((unsigned short*)Cout)[(size_t)grow * F + col] = f2b(v);
                else         ((float*)Cout)[(size_t)grow * F + col] = v;
            }
        }
    }
}

extern "C" void kernel_launch(void* const* d_in, const int* in_sizes, int n_in,
                              void* d_out, int out_size, void* d_ws, size_t ws_size,
                              hipStream_t stream) {
    const float* feat_c = (const float*)d_in[0];
    const float* feat_s = (const float*)d_in[1];
    const int*   idx_k1 = (const int*)d_in[2];
    const int*   idx_k2 = (const int*)d_in[3];
    const float* W1     = (const float*)d_in[4];
    const float* b1     = (const float*)d_in[5];
    const float* W2     = (const float*)d_in[6];
    const float* b2     = (const float*)d_in[7];

    char* ws = (char*)d_ws;
    int*            deg  = (int*)ws;                                    // 256 KB
    unsigned short* Wp1  = (unsigned short*)(ws + 262144);
    unsigned short* Wp2  = (unsigned short*)(ws + 262144 + 165888);
    unsigned short* aggb = (unsigned short*)(ws + 262144 + 2 * 165888); // 18.9 MB

    unsigned short* featb = (unsigned short*)d_out;  // 37.75 MB bf16 table
    unsigned short* h1b   = (unsigned short*)d_out;  // first 18.9 MB, after agg1 done
    float*          out   = (float*)d_out;

    hipMemsetAsync(deg, 0, (size_t)B * NT * sizeof(int), stream);
    prep_kernel<<<PREP_CVT + PREP_DEG + PREP_PKW, 256, 0, stream>>>(
        idx_k1, idx_k2, deg, feat_c, feat_s, featb, W1, W2, Wp1, Wp2);

    agg_kernel<1><<<BM / 16, 256, 0, stream>>>(featb, idx_k1, idx_k2, deg, b1, aggb);
    gemm_kernel<1, 1><<<BM / 64, 256, 0, stream>>>(aggb, Wp1, b1, (void*)h1b);

    agg_kernel<2><<<BM / 16, 256, 0, stream>>>(h1b, idx_k1, idx_k2, deg, b1, aggb);
    gemm_kernel<0, 0><<<BM / 64, 256, 0, stream>>>(aggb, Wp2, b2, (void*)out);
}